// Round 4
// baseline (762.326 us; speedup 1.0000x reference)
//
#include <hip/hip_runtime.h>
#include <math.h>

// ArcFaceLoss: B=512, D=512, C=100000, margin=0.5, scale=64
// R4: barrierless, LDS-free GEMM. Both operands direct-to-register in MFMA
// fragment layout. A (normalized x, bf16, 512 KB) prepacked in fragment order,
// served from L2/L3. B (W, fp32) streamed from HBM exactly once, fragment-shaped
// coalesced loads (16 rows x 128 B per n-tile per K-step), normalized on the fly
// (sumsq in regs, rsqrt in epilogue). Software pipeline depth 1, no __syncthreads
// in the K-loop, #pragma unroll 2 (NEVER full unroll -> R3's spill disaster).

#define NB 512
#define ND 512
#define NC 100000
#define CT 128               // classes per block
#define NBLK 782             // ceil(NC/CT)
#define FSCALE 64.0f
#define C_COS_M 0.8775825618903728f
#define C_SIN_M 0.479425538604203f
#define C_TH  (-0.8775825618903728f)
#define C_MM  0.2397127693021015f

typedef __bf16 bf16x8 __attribute__((ext_vector_type(8)));
typedef __bf16 bf16x4 __attribute__((ext_vector_type(4)));
typedef float  f32x4  __attribute__((ext_vector_type(4)));

// xp fragment layout: element index = ((kk*32 + mt_g)*64 + lane)*8 + j
//   lane = q*16 + ra holds A[row = mt_g*16 + ra][k = kk*32 + q*8 + j], j=0..7
// -> per (mt_g,kk) a wave reads 64 lanes x 16 B = 1 KB contiguous.

// ---------------- 1) prep: normalize+pack x, target cos/phi, zero gsum ----------------
__global__ void prep_kernel(const float* __restrict__ x, const float* __restrict__ w,
                            const int* __restrict__ tgt, __bf16* __restrict__ xp,
                            float* __restrict__ cos_t, float* __restrict__ phi_t,
                            float* __restrict__ gsum) {
  const int b = blockIdx.x;
  const int t = threadIdx.x;                   // 0..127, covers k=4t..4t+3
  const int tg = tgt[b];
  float4 v  = reinterpret_cast<const float4*>(x + (size_t)b * ND)[t];
  float4 wv = reinterpret_cast<const float4*>(w + (size_t)tg * ND)[t];
  float ss = v.x*v.x + v.y*v.y + v.z*v.z + v.w*v.w;
  float dp = v.x*wv.x + v.y*wv.y + v.z*wv.z + v.w*wv.w;
  float ws = wv.x*wv.x + wv.y*wv.y + wv.z*wv.z + wv.w*wv.w;
  #pragma unroll
  for (int m = 1; m < 64; m <<= 1) {
    ss += __shfl_xor(ss, m);
    dp += __shfl_xor(dp, m);
    ws += __shfl_xor(ws, m);
  }
  __shared__ float s3[2][3];
  if ((t & 63) == 0) { s3[t >> 6][0] = ss; s3[t >> 6][1] = dp; s3[t >> 6][2] = ws; }
  __syncthreads();
  const float fss = s3[0][0] + s3[1][0];
  const float fdp = s3[0][1] + s3[1][1];
  const float fws = s3[0][2] + s3[1][2];
  const float rn = rsqrtf(fmaxf(fss, 1e-24f));
  // pack
  bf16x4 o;
  o[0] = (__bf16)(v.x * rn); o[1] = (__bf16)(v.y * rn);
  o[2] = (__bf16)(v.z * rn); o[3] = (__bf16)(v.w * rn);
  const int mt_g = b >> 4, ra = b & 15;
  const int k = 4 * t;
  const int kk = k >> 5;
  const int q  = (k >> 3) & 3;
  const int j  = k & 7;                        // 0 or 4
  const int lane_f = q * 16 + ra;
  __bf16* dst = xp + ((size_t)(kk * 32 + mt_g) * 64 + lane_f) * 8 + j;
  *reinterpret_cast<bf16x4*>(dst) = o;
  if (t == 0) {
    float c = fdp * rsqrtf(fmaxf(fss, 1e-24f)) * rsqrtf(fmaxf(fws, 1e-24f));
    c = fminf(fmaxf(c, -1.f), 1.f);
    float s = sqrtf(fmaxf(1.f - c * c, 0.f));
    float phi = c * C_COS_M - s * C_SIN_M;
    phi = (c > C_TH) ? phi : (c - C_MM);
    cos_t[b] = c;
    phi_t[b] = phi;
    gsum[b] = 0.f;
  }
}

// ---------------- 2) barrierless GEMM + partial sum-exp ----------------
// Block: 512 threads (8 waves) = 4 m-groups x 2 n-groups over 512 rows x 128 cols.
// Wave (mg,ng): rows [mg*128, +128) = 8 m-tiles, cols [blk*128+ng*64, +64) = 4 n-tiles.
// acc = 8x4 f32x4 = 128 regs (AGPR). K-loop: 16 steps of K=32, fully streaming.
__global__ __launch_bounds__(512, 2) void gemm_lse_kernel(
    const __bf16* __restrict__ xp, const float* __restrict__ w,
    float* __restrict__ gsum) {
  const int tid  = threadIdx.x;
  const int wv   = tid >> 6;
  const int lane = tid & 63;
  const int mg   = wv & 3;          // m-group
  const int ng   = wv >> 2;         // n-group
  const int ra   = lane & 15;
  const int q    = lane >> 4;
  const int c0   = blockIdx.x * CT + ng * 64;

  // B row base pointers (per n-tile), clamped; validity masked in epilogue
  const float* wrow[4];
  int valid[4];
  #pragma unroll
  for (int nt = 0; nt < 4; ++nt) {
    const int n = c0 + nt * 16 + ra;
    valid[nt] = n < NC;
    wrow[nt] = w + (size_t)(valid[nt] ? n : (NC - 1)) * ND + q * 8;
  }
  // A fragment base for this wave: elem ((kk*32 + mg*8+mt)*64 + lane)*8
  const bf16x8* afrag = reinterpret_cast<const bf16x8*>(xp) + (size_t)(mg * 8) * 64 + lane;

  f32x4 acc[8][4] = {};
  float wsq[4] = {0.f, 0.f, 0.f, 0.f};

  bf16x8 a_cur[8], a_next[8];
  float4 b32[4][2];
  bf16x8 b16[4];

  // prologue: loads for kk = 0
  #pragma unroll
  for (int mt = 0; mt < 8; ++mt) a_cur[mt] = afrag[mt * 64];
  #pragma unroll
  for (int nt = 0; nt < 4; ++nt) {
    b32[nt][0] = *reinterpret_cast<const float4*>(wrow[nt]);
    b32[nt][1] = *reinterpret_cast<const float4*>(wrow[nt] + 4);
  }

  #pragma unroll 2
  for (int kk = 0; kk < 16; ++kk) {
    // convert B to bf16, accumulate sumsq (frees b32 for refill)
    #pragma unroll
    for (int nt = 0; nt < 4; ++nt) {
      const float4 u = b32[nt][0], t4 = b32[nt][1];
      wsq[nt] += u.x*u.x + u.y*u.y + u.z*u.z + u.w*u.w
               + t4.x*t4.x + t4.y*t4.y + t4.z*t4.z + t4.w*t4.w;
      bf16x8 ob;
      ob[0] = (__bf16)u.x;  ob[1] = (__bf16)u.y;  ob[2] = (__bf16)u.z;  ob[3] = (__bf16)u.w;
      ob[4] = (__bf16)t4.x; ob[5] = (__bf16)t4.y; ob[6] = (__bf16)t4.z; ob[7] = (__bf16)t4.w;
      b16[nt] = ob;
    }
    // issue next step's loads (covered by the 32 MFMAs below)
    if (kk < 15) {
      #pragma unroll
      for (int nt = 0; nt < 4; ++nt) {
        b32[nt][0] = *reinterpret_cast<const float4*>(wrow[nt] + (kk + 1) * 32);
        b32[nt][1] = *reinterpret_cast<const float4*>(wrow[nt] + (kk + 1) * 32 + 4);
      }
      #pragma unroll
      for (int mt = 0; mt < 8; ++mt) a_next[mt] = afrag[(size_t)(kk + 1) * 32 * 64 + mt * 64];
    }
    // 32 MFMA
    #pragma unroll
    for (int nt = 0; nt < 4; ++nt)
      #pragma unroll
      for (int mt = 0; mt < 8; ++mt)
        acc[mt][nt] = __builtin_amdgcn_mfma_f32_16x16x32_bf16(a_cur[mt], b16[nt],
                                                              acc[mt][nt], 0, 0, 0);
    #pragma unroll
    for (int mt = 0; mt < 8; ++mt) a_cur[mt] = a_next[mt];
  }

  // finish ||w||^2: reduce over the 4 quads holding the same row
  float rnw[4];
  #pragma unroll
  for (int nt = 0; nt < 4; ++nt) {
    float s = wsq[nt];
    s += __shfl_xor(s, 16);
    s += __shfl_xor(s, 32);
    rnw[nt] = rsqrtf(fmaxf(s, 1e-24f));
  }

  // epilogue: cos = acc * rnw; e = exp(64cos-64); sum over 64 cols -> atomic per row
  // C/D 16x16 layout: col = ra, row = q*4 + r
  #pragma unroll
  for (int mt = 0; mt < 8; ++mt) {
    #pragma unroll
    for (int r = 0; r < 4; ++r) {
      float es = 0.f;
      #pragma unroll
      for (int nt = 0; nt < 4; ++nt) {
        float e = __expf(fmaf(FSCALE, acc[mt][nt][r] * rnw[nt], -FSCALE));
        es += valid[nt] ? e : 0.f;
      }
      es += __shfl_xor(es, 1);
      es += __shfl_xor(es, 2);
      es += __shfl_xor(es, 4);
      es += __shfl_xor(es, 8);
      if (ra == 0)
        atomicAdd(&gsum[mg * 128 + mt * 16 + q * 4 + r], es);
    }
  }
}

// ---------------- 3) finalize ----------------
__global__ void finalize_kernel(const float* __restrict__ gsum,
                                const float* __restrict__ cos_t,
                                const float* __restrict__ phi_t,
                                float* __restrict__ out) {
  const int b = threadIdx.x;   // 512
  const float c = cos_t[b];
  const float p = phi_t[b];
  float corr = gsum[b] - __expf(fmaf(FSCALE, c, -FSCALE))
                       + __expf(fmaf(FSCALE, p, -FSCALE));
  corr = fmaxf(corr, 1e-38f);
  float lb = FSCALE + logf(corr) - FSCALE * p;
  #pragma unroll
  for (int m = 1; m < 64; m <<= 1) lb += __shfl_xor(lb, m);
  __shared__ float pr[8];
  if ((b & 63) == 0) pr[b >> 6] = lb;
  __syncthreads();
  if (b == 0) {
    float tot = 0.f;
    #pragma unroll
    for (int j = 0; j < 8; ++j) tot += pr[j];
    out[0] = tot * (1.0f / NB);
  }
}

extern "C" void kernel_launch(void* const* d_in, const int* in_sizes, int n_in,
                              void* d_out, int out_size, void* d_ws, size_t ws_size,
                              hipStream_t stream) {
  const float* x  = (const float*)d_in[0];
  const float* w  = (const float*)d_in[1];
  const int* tgt  = (const int*)d_in[2];
  float* out      = (float*)d_out;

  // workspace: xp (512 KB) | gsum (2 KB) | cos_t (2 KB) | phi_t (2 KB)
  const size_t XP_BYTES = (size_t)NB * ND * 2;
  __bf16* xp   = (__bf16*)d_ws;
  float* gsum  = (float*)((char*)d_ws + XP_BYTES);
  float* cos_t = gsum + NB;
  float* phi_t = cos_t + NB;

  prep_kernel<<<NB, 128, 0, stream>>>(x, w, tgt, xp, cos_t, phi_t, gsum);
  gemm_lse_kernel<<<NBLK, 512, 0, stream>>>(xp, w, gsum);
  finalize_kernel<<<1, 512, 0, stream>>>(gsum, cos_t, phi_t, out);
}